// Round 5
// baseline (282.819 us; speedup 1.0000x reference)
//
#include <hip/hip_runtime.h>
#include <hip/hip_bf16.h>

typedef _Float16 half8 __attribute__((ext_vector_type(8)));
typedef _Float16 half2v __attribute__((ext_vector_type(2)));
typedef __fp16 fp16x2 __attribute__((ext_vector_type(2)));
typedef float f32x4 __attribute__((ext_vector_type(4)));

#define BH_ 64
#define L_ 1024
#define DK_ 64

__device__ __forceinline__ unsigned short f2h(float f) {
    _Float16 h = (_Float16)f;
    return __builtin_bit_cast(unsigned short, h);
}
__device__ __forceinline__ unsigned int pk2h(float a, float b) {
    fp16x2 h = __builtin_amdgcn_cvt_pkrtz(a, b);
    return __builtin_bit_cast(unsigned int, h);
}

// ---------------- prep: K -> fp16 ----------------
__global__ void prep_k(const float* __restrict__ K, unsigned short* __restrict__ Kh) {
    int idx = blockIdx.x * 256 + threadIdx.x;  // one float4 each; grid sized exactly
    float4 v = reinterpret_cast<const float4*>(K)[idx];
    ushort4 o;
    o.x = f2h(v.x); o.y = f2h(v.y); o.z = f2h(v.z); o.w = f2h(v.w);
    reinterpret_cast<ushort4*>(Kh)[idx] = o;
}

// ---------------- prep: V -> Vt fp16 transposed [bh][n][k] ----------------
__global__ void prep_v(const float* __restrict__ V, unsigned short* __restrict__ Vt) {
    __shared__ float lds[64][65];
    int bh = blockIdx.x >> 4, kt = blockIdx.x & 15;
    int t = threadIdx.x;
    const float* Vb = V + ((size_t)bh * L_ + kt * 64) * DK_;
#pragma unroll
    for (int it = 0; it < 4; ++it) {
        int idx = it * 256 + t;  // 1024 float4 = 64x64 tile
        int row = idx >> 4, c4 = idx & 15;
        float4 v = reinterpret_cast<const float4*>(Vb + (size_t)row * DK_)[c4];
        lds[row][c4 * 4 + 0] = v.x; lds[row][c4 * 4 + 1] = v.y;
        lds[row][c4 * 4 + 2] = v.z; lds[row][c4 * 4 + 3] = v.w;
    }
    __syncthreads();
    unsigned short* Vtb = Vt + (size_t)bh * 64 * L_ + kt * 64;
#pragma unroll
    for (int it = 0; it < 4; ++it) {
        int idx = it * 256 + t;
        int n = idx >> 4, c4 = idx & 15;
        ushort4 o;
        o.x = f2h(lds[c4 * 4 + 0][n]);
        o.y = f2h(lds[c4 * 4 + 1][n]);
        o.z = f2h(lds[c4 * 4 + 2][n]);
        o.w = f2h(lds[c4 * 4 + 3][n]);
        *reinterpret_cast<ushort4*>(Vtb + (size_t)n * L_ + c4 * 4) = o;
    }
}

// ---------------- prep: mask int32 -> bitmask (1 bit/elem) ----------------
// Pure streaming: 268 MB read -> 8.4 MB write at HBM BW. Lane packs 32 ints.
__global__ void prep_m(const int* __restrict__ mask, unsigned int* __restrict__ mbits) {
    int gid = blockIdx.x * 256 + threadIdx.x;  // one output word per lane
    const int* p = mask + (size_t)gid * 32;
    unsigned int wd = 0;
#pragma unroll
    for (int j = 0; j < 8; ++j) {
        int4 v = *reinterpret_cast<const int4*>(p + j * 4);
        wd |= (v.x ? 1u : 0u) << (j * 4 + 0);
        wd |= (v.y ? 1u : 0u) << (j * 4 + 1);
        wd |= (v.z ? 1u : 0u) << (j * 4 + 2);
        wd |= (v.w ? 1u : 0u) << (j * 4 + 3);
    }
    mbits[gid] = wd;
}

// ---------------- main fused attention ----------------
// WG = 16 q-rows, 4 waves; wave w owns k in [w*256, w*256+256).
// S^T tiles via mfma(Kfrag, Qfrag): lane holds q=lane&15, k=k0+4*(lane>>4)+r.
// Mask comes from the 8.4 MB bitmask: per lane, 8 words loaded ONCE cover its
// entire k-range -> zero mask traffic in the QK loop. Scores packed fp16.
__global__ __launch_bounds__(256, 5) void attn_main(
    const float* __restrict__ Q, const unsigned int* __restrict__ mbits,
    const unsigned short* __restrict__ Kh, const unsigned short* __restrict__ Vt,
    float* __restrict__ ctx_out, float* __restrict__ attn_out)
{
    const int qt = blockIdx.x, bh = blockIdx.y;
    const int tid = threadIdx.x;
    const int w = tid >> 6;
    const int lane = tid & 63;
    const int lg = lane >> 4, lr = lane & 15;
    const int q0 = qt * 16;

    __shared__ float red[2][4][16];
    __shared__ union {
        unsigned short pbuf[4][640];
        float ctxbuf[4][16][68];
    } u;

    // Q B-frag: lane holds Q[q0+lr][f*32 + lg*8 + j], fp16
    half8 qh[2];
    {
        const float* qp = Q + ((size_t)bh * L_ + q0 + lr) * DK_ + lg * 8;
#pragma unroll
        for (int f = 0; f < 2; ++f) {
            float4 a = *reinterpret_cast<const float4*>(qp + f * 32);
            float4 b = *reinterpret_cast<const float4*>(qp + f * 32 + 4);
            qh[f][0] = (_Float16)a.x; qh[f][1] = (_Float16)a.y;
            qh[f][2] = (_Float16)a.z; qh[f][3] = (_Float16)a.w;
            qh[f][4] = (_Float16)b.x; qh[f][5] = (_Float16)b.y;
            qh[f][6] = (_Float16)b.z; qh[f][7] = (_Float16)b.w;
        }
    }

    // Per-lane mask bits: row (q0+lr), k in [w*256, w*256+256) = 8 words.
    const unsigned int* mb = mbits + ((size_t)bh * L_ + q0 + lr) * (L_ / 32) + w * 8;
    uint4 mw0 = *reinterpret_cast<const uint4*>(mb);
    uint4 mw1 = *reinterpret_cast<const uint4*>(mb + 4);
    const unsigned int mwords[8] = {mw0.x, mw0.y, mw0.z, mw0.w,
                                    mw1.x, mw1.y, mw1.z, mw1.w};

    const size_t rowbase = ((size_t)bh * L_ + q0 + lr) * L_;  // [bh][q][*] attn row
    const unsigned short* kp = Kh + ((size_t)bh * L_ + w * 256 + lr) * DK_ + lg * 8;

    // ---- QK^T: K depth-2 pipeline (L2-resident), mask from registers ----
    unsigned int sh[16][2];
    float mx = -INFINITY;

    half8 kc0 = *reinterpret_cast<const half8*>(kp);
    half8 kc1 = *reinterpret_cast<const half8*>(kp + 32);

#pragma unroll
    for (int tt = 0; tt < 16; ++tt) {
        half8 kn0 = kc0, kn1 = kc1;
        if (tt < 15) {
            kn0 = *reinterpret_cast<const half8*>(kp + (tt + 1) * 1024);
            kn1 = *reinterpret_cast<const half8*>(kp + (tt + 1) * 1024 + 32);
        }
        f32x4 acc = {0.f, 0.f, 0.f, 0.f};
        acc = __builtin_amdgcn_mfma_f32_16x16x32_f16(kc0, qh[0], acc, 0, 0, 0);
        acc = __builtin_amdgcn_mfma_f32_16x16x32_f16(kc1, qh[1], acc, 0, 0, 0);
        const unsigned int word = mwords[tt >> 1];
        const unsigned int sh4 = (tt & 1) * 16 + lg * 4;
        float s0 = ((word >> (sh4 + 0)) & 1u) ? -INFINITY : 0.25f * acc[0];
        float s1 = ((word >> (sh4 + 1)) & 1u) ? -INFINITY : 0.25f * acc[1];
        float s2 = ((word >> (sh4 + 2)) & 1u) ? -INFINITY : 0.25f * acc[2];
        float s3 = ((word >> (sh4 + 3)) & 1u) ? -INFINITY : 0.25f * acc[3];
        sh[tt][0] = pk2h(s0, s1);
        sh[tt][1] = pk2h(s2, s3);
        mx = fmaxf(mx, fmaxf(fmaxf(s0, s1), fmaxf(s2, s3)));
        kc0 = kn0; kc1 = kn1;
    }

    // ---- softmax: row max across lg groups, then across waves ----
    mx = fmaxf(mx, __shfl_xor(mx, 16));
    mx = fmaxf(mx, __shfl_xor(mx, 32));
    if (lane < 16) red[0][w][lr] = mx;
    __syncthreads();
    const float gm = fmaxf(fmaxf(red[0][0][lr], red[0][1][lr]),
                           fmaxf(red[0][2][lr], red[0][3][lr]));

    // ---- exp + row sum; p stays packed fp16 (unnormalized) ----
    float lsum = 0.f;
#pragma unroll
    for (int tt = 0; tt < 16; ++tt) {
        half2v a = __builtin_bit_cast(half2v, sh[tt][0]);
        half2v b = __builtin_bit_cast(half2v, sh[tt][1]);
        float p0 = __expf((float)a[0] - gm);
        float p1 = __expf((float)a[1] - gm);
        float p2 = __expf((float)b[0] - gm);
        float p3 = __expf((float)b[1] - gm);
        lsum += (p0 + p1) + (p2 + p3);
        sh[tt][0] = pk2h(p0, p1);
        sh[tt][1] = pk2h(p2, p3);
    }
    lsum += __shfl_xor(lsum, 16);
    lsum += __shfl_xor(lsum, 32);
    if (lane < 16) red[1][w][lr] = lsum;
    __syncthreads();
    const float gsum = red[1][0][lr] + red[1][1][lr] + red[1][2][lr] + red[1][3][lr];
    const float rinv = 1.0f / gsum;

    // ---- PV (unnormalized p, per-wave LDS bounce); no global stores here ----
    f32x4 cacc[4] = {{0,0,0,0},{0,0,0,0},{0,0,0,0},{0,0,0,0}};
    unsigned short* pb = &u.pbuf[w][0];
    const unsigned short* vp = Vt + ((size_t)bh * 64 + lr) * L_ + w * 256 + lg * 8;

    half8 vb0 = *reinterpret_cast<const half8*>(vp);
    half8 vb1 = *reinterpret_cast<const half8*>(vp + 16384);
    half8 vb2 = *reinterpret_cast<const half8*>(vp + 32768);
    half8 vb3 = *reinterpret_cast<const half8*>(vp + 49152);

#pragma unroll
    for (int c = 0; c < 8; ++c) {
        half8 vn0 = vb0, vn1 = vb1, vn2 = vb2, vn3 = vb3;
        if (c < 7) {
            vn0 = *reinterpret_cast<const half8*>(vp + (c + 1) * 32);
            vn1 = *reinterpret_cast<const half8*>(vp + 16384 + (c + 1) * 32);
            vn2 = *reinterpret_cast<const half8*>(vp + 32768 + (c + 1) * 32);
            vn3 = *reinterpret_cast<const half8*>(vp + 49152 + (c + 1) * 32);
        }
#pragma unroll
        for (int t2 = 0; t2 < 2; ++t2) {
            const int tt = 2 * c + t2;
            uint2 pr; pr.x = sh[tt][0]; pr.y = sh[tt][1];
            *reinterpret_cast<uint2*>(&pb[lr * 40 + t2 * 16 + lg * 4]) = pr;
        }
        // A-frag read: p[q=lr][k32 = lg*8 + j] (wave-private LDS, in-order)
        half8 pa = *reinterpret_cast<const half8*>(&pb[lr * 40 + lg * 8]);
        cacc[0] = __builtin_amdgcn_mfma_f32_16x16x32_f16(pa, vb0, cacc[0], 0, 0, 0);
        cacc[1] = __builtin_amdgcn_mfma_f32_16x16x32_f16(pa, vb1, cacc[1], 0, 0, 0);
        cacc[2] = __builtin_amdgcn_mfma_f32_16x16x32_f16(pa, vb2, cacc[2], 0, 0, 0);
        cacc[3] = __builtin_amdgcn_mfma_f32_16x16x32_f16(pa, vb3, cacc[3], 0, 0, 0);
        vb0 = vn0; vb1 = vn1; vb2 = vn2; vb3 = vn3;
    }

    // ---- attn write pass (normalized), pure store stream ----
#pragma unroll
    for (int tt = 0; tt < 16; ++tt) {
        half2v a = __builtin_bit_cast(half2v, sh[tt][0]);
        half2v b = __builtin_bit_cast(half2v, sh[tt][1]);
        float4 av;
        av.x = (float)a[0] * rinv; av.y = (float)a[1] * rinv;
        av.z = (float)b[0] * rinv; av.w = (float)b[1] * rinv;
        *reinterpret_cast<float4*>(&attn_out[rowbase + w * 256 + tt * 16 + lg * 4]) = av;
    }

    // ---- combine partial contexts across waves, normalize by 1/sum ----
    __syncthreads();  // all waves done with u.pbuf before u.ctxbuf overwrites it
#pragma unroll
    for (int nt = 0; nt < 4; ++nt)
#pragma unroll
        for (int r = 0; r < 4; ++r)
            u.ctxbuf[w][lg * 4 + r][nt * 16 + lr] = cacc[nt][r];
    __syncthreads();
    {
        int e = tid * 4;
        int q = e >> 6, n = e & 63;
        float gs = red[1][0][q] + red[1][1][q] + red[1][2][q] + red[1][3][q];
        float rq = 1.0f / gs;
        float4 a0 = *reinterpret_cast<float4*>(&u.ctxbuf[0][q][n]);
        float4 a1 = *reinterpret_cast<float4*>(&u.ctxbuf[1][q][n]);
        float4 a2 = *reinterpret_cast<float4*>(&u.ctxbuf[2][q][n]);
        float4 a3 = *reinterpret_cast<float4*>(&u.ctxbuf[3][q][n]);
        float4 o;
        o.x = (a0.x + a1.x + a2.x + a3.x) * rq;
        o.y = (a0.y + a1.y + a2.y + a3.y) * rq;
        o.z = (a0.z + a1.z + a2.z + a3.z) * rq;
        o.w = (a0.w + a1.w + a2.w + a3.w) * rq;
        *reinterpret_cast<float4*>(&ctx_out[((size_t)bh * L_ + q0 + q) * DK_ + n]) = o;
    }
}

extern "C" void kernel_launch(void* const* d_in, const int* in_sizes, int n_in,
                              void* d_out, int out_size, void* d_ws, size_t ws_size,
                              hipStream_t stream) {
    const float* Q = (const float*)d_in[0];
    const float* K = (const float*)d_in[1];
    const float* V = (const float*)d_in[2];
    const int* mask = (const int*)d_in[3];
    float* ctx_out = (float*)d_out;
    float* attn_out = ctx_out + (size_t)BH_ * L_ * DK_;

    unsigned short* Kh = (unsigned short*)d_ws;
    unsigned short* Vt = Kh + (size_t)BH_ * L_ * DK_;
    unsigned int* mbits = (unsigned int*)(Vt + (size_t)BH_ * L_ * DK_);

    hipLaunchKernelGGL(prep_k, dim3(4096), dim3(256), 0, stream, K, Kh);
    hipLaunchKernelGGL(prep_v, dim3(1024), dim3(256), 0, stream, V, Vt);
    hipLaunchKernelGGL(prep_m, dim3(8192), dim3(256), 0, stream, mask, mbits);
    hipLaunchKernelGGL(attn_main, dim3(64, 64), dim3(256), 0, stream,
                       Q, mbits, Kh, Vt, ctx_out, attn_out);
}

// Round 6
// 212.163 us; speedup vs baseline: 1.3330x; 1.3330x over previous
//
#include <hip/hip_runtime.h>
#include <hip/hip_bf16.h>

typedef _Float16 half8 __attribute__((ext_vector_type(8)));
typedef _Float16 half2v __attribute__((ext_vector_type(2)));
typedef __fp16 fp16x2 __attribute__((ext_vector_type(2)));
typedef float f32x4 __attribute__((ext_vector_type(4)));
typedef int i32x4 __attribute__((ext_vector_type(4)));

#define BH_ 64
#define L_ 1024
#define DK_ 64

__device__ __forceinline__ unsigned short f2h(float f) {
    _Float16 h = (_Float16)f;
    return __builtin_bit_cast(unsigned short, h);
}
__device__ __forceinline__ unsigned int pk2h(float a, float b) {
    fp16x2 h = __builtin_amdgcn_cvt_pkrtz(a, b);
    return __builtin_bit_cast(unsigned int, h);
}

// ---- inline-asm load/wait machinery ----
// Rounds 3-5 evidence: compiler sinks ALL plain-HIP prefetch loads to use
// sites (VGPR stuck at 48). asm volatile loads are pinned in program order
// among themselves; explicit literal vmcnt waits; sched_barrier(0) after
// each wait per rule #18 (stops MFMA hoisting above the wait).
template<int OFF>
__device__ __forceinline__ void gl_h8(half8& d, const unsigned short* p) {
    asm volatile("global_load_dwordx4 %0, %1, off offset:%2"
                 : "=&v"(d) : "v"(p), "n"(OFF));
}
template<int OFF>
__device__ __forceinline__ void gl_i4(i32x4& d, const int* p) {
    asm volatile("global_load_dwordx4 %0, %1, off offset:%2"
                 : "=&v"(d) : "v"(p), "n"(OFF));
}
template<int OFF>
__device__ __forceinline__ void gl_f4(f32x4& d, const float* p) {
    asm volatile("global_load_dwordx4 %0, %1, off offset:%2"
                 : "=&v"(d) : "v"(p), "n"(OFF));
}
template<int N>
__device__ __forceinline__ void wait_vm() {
    asm volatile("s_waitcnt vmcnt(%0)" :: "n"(N) : "memory");
    __builtin_amdgcn_sched_barrier(0);
}

// ---------------- prep: K -> fp16 ----------------
__global__ void prep_k(const float* __restrict__ K, unsigned short* __restrict__ Kh) {
    int idx = blockIdx.x * 256 + threadIdx.x;
    float4 v = reinterpret_cast<const float4*>(K)[idx];
    ushort4 o;
    o.x = f2h(v.x); o.y = f2h(v.y); o.z = f2h(v.z); o.w = f2h(v.w);
    reinterpret_cast<ushort4*>(Kh)[idx] = o;
}

// ---------------- prep: V -> Vt fp16 transposed [bh][n][k] ----------------
__global__ void prep_v(const float* __restrict__ V, unsigned short* __restrict__ Vt) {
    __shared__ float lds[64][65];
    int bh = blockIdx.x >> 4, kt = blockIdx.x & 15;
    int t = threadIdx.x;
    const float* Vb = V + ((size_t)bh * L_ + kt * 64) * DK_;
#pragma unroll
    for (int it = 0; it < 4; ++it) {
        int idx = it * 256 + t;
        int row = idx >> 4, c4 = idx & 15;
        float4 v = reinterpret_cast<const float4*>(Vb + (size_t)row * DK_)[c4];
        lds[row][c4 * 4 + 0] = v.x; lds[row][c4 * 4 + 1] = v.y;
        lds[row][c4 * 4 + 2] = v.z; lds[row][c4 * 4 + 3] = v.w;
    }
    __syncthreads();
    unsigned short* Vtb = Vt + (size_t)bh * 64 * L_ + kt * 64;
#pragma unroll
    for (int it = 0; it < 4; ++it) {
        int idx = it * 256 + t;
        int n = idx >> 4, c4 = idx & 15;
        ushort4 o;
        o.x = f2h(lds[c4 * 4 + 0][n]);
        o.y = f2h(lds[c4 * 4 + 1][n]);
        o.z = f2h(lds[c4 * 4 + 2][n]);
        o.w = f2h(lds[c4 * 4 + 3][n]);
        *reinterpret_cast<ushort4*>(Vtb + (size_t)n * L_ + c4 * 4) = o;
    }
}

// ---------------- main fused attention ----------------
// WG = 16 q-rows, 4 waves; wave w owns k in [w*256, w*256+256).
// All QK/PV-phase vmem is inline-asm with exact FIFO vmcnt accounting.
// Issue order: mask(16), Q(4), K-chunk0(8) => 28 outstanding.
__global__ __launch_bounds__(256, 3) void attn_main(
    const float* __restrict__ Q, const int* __restrict__ mask,
    const unsigned short* __restrict__ Kh, const unsigned short* __restrict__ Vt,
    float* __restrict__ ctx_out, float* __restrict__ attn_out)
{
    const int qt = blockIdx.x, bh = blockIdx.y;
    const int tid = threadIdx.x;
    const int w = tid >> 6;
    const int lane = tid & 63;
    const int lg = lane >> 4, lr = lane & 15;
    const int q0 = qt * 16;

    __shared__ float red[2][4][16];
    __shared__ union {
        unsigned short pbuf[4][640];
        float ctxbuf[4][16][68];
    } u;

    const size_t rowbase = ((size_t)bh * L_ + q0 + lr) * L_;
    const float* qp = Q + ((size_t)bh * L_ + q0 + lr) * DK_ + lg * 8;
    const int* mp = mask + rowbase + w * 256 + lg * 4;
    const unsigned short* kp = Kh + ((size_t)bh * L_ + w * 256 + lr) * DK_ + lg * 8;

    // ---- issue burst: mask(16) + Q(4) + K chunk0(8) ----
    i32x4 mreg[16];
#define LM(T) gl_i4<(T) * 64>(mreg[T], mp)
    LM(0); LM(1); LM(2); LM(3); LM(4); LM(5); LM(6); LM(7);
    LM(8); LM(9); LM(10); LM(11); LM(12); LM(13); LM(14); LM(15);
#undef LM
    f32x4 qf0, qf1, qf2, qf3;
    gl_f4<0>(qf0, qp); gl_f4<16>(qf1, qp);
    gl_f4<128>(qf2, qp); gl_f4<144>(qf3, qp);

    half8 ka[2][4], kb[2][4];
    // K tile stride = 1024 shorts = 2048B; chunk = 4 tiles = 4096 shorts.
#define ISSUE_K(BUF, C) { \
    const unsigned short* a0_ = kp + (C) * 4096; \
    const unsigned short* a2_ = a0_ + 2048; \
    gl_h8<0>(ka[BUF][0], a0_);    gl_h8<64>(kb[BUF][0], a0_); \
    gl_h8<2048>(ka[BUF][1], a0_); gl_h8<2112>(kb[BUF][1], a0_); \
    gl_h8<0>(ka[BUF][2], a2_);    gl_h8<64>(kb[BUF][2], a2_); \
    gl_h8<2048>(ka[BUF][3], a2_); gl_h8<2112>(kb[BUF][3], a2_); }
    ISSUE_K(0, 0);                 // outstanding: 16m + 4q + 8k = 28

    wait_vm<12>();                 // completes 16 oldest = mask
    unsigned int mw0 = 0, mw1 = 0; // bit ((tt&7)*4 + r), word = tt>=8
#pragma unroll
    for (int t = 0; t < 8; ++t) {
        mw0 |= (unsigned(mreg[t][0] != 0) << (t * 4 + 0))
             | (unsigned(mreg[t][1] != 0) << (t * 4 + 1))
             | (unsigned(mreg[t][2] != 0) << (t * 4 + 2))
             | (unsigned(mreg[t][3] != 0) << (t * 4 + 3));
        mw1 |= (unsigned(mreg[t + 8][0] != 0) << (t * 4 + 0))
             | (unsigned(mreg[t + 8][1] != 0) << (t * 4 + 1))
             | (unsigned(mreg[t + 8][2] != 0) << (t * 4 + 2))
             | (unsigned(mreg[t + 8][3] != 0) << (t * 4 + 3));
    }

    wait_vm<8>();                  // completes Q (4)
    half8 qh[2];
#pragma unroll
    for (int j = 0; j < 4; ++j) {
        qh[0][j]     = (_Float16)qf0[j];
        qh[0][j + 4] = (_Float16)qf1[j];
        qh[1][j]     = (_Float16)qf2[j];
        qh[1][j + 4] = (_Float16)qf3[j];
    }

    ISSUE_K(1, 1);                 // outstanding: K0(8) + K1(8) = 16

    unsigned int sh[16][2];
    float mx = -INFINITY;
#define QK_TILE(BUF, T, TT) { \
    f32x4 acc_ = {0.f, 0.f, 0.f, 0.f}; \
    acc_ = __builtin_amdgcn_mfma_f32_16x16x32_f16(ka[BUF][T], qh[0], acc_, 0, 0, 0); \
    acc_ = __builtin_amdgcn_mfma_f32_16x16x32_f16(kb[BUF][T], qh[1], acc_, 0, 0, 0); \
    const unsigned int word_ = ((TT) < 8) ? mw0 : mw1; \
    float s0_ = ((word_ >> (((TT) & 7) * 4 + 0)) & 1u) ? -INFINITY : 0.25f * acc_[0]; \
    float s1_ = ((word_ >> (((TT) & 7) * 4 + 1)) & 1u) ? -INFINITY : 0.25f * acc_[1]; \
    float s2_ = ((word_ >> (((TT) & 7) * 4 + 2)) & 1u) ? -INFINITY : 0.25f * acc_[2]; \
    float s3_ = ((word_ >> (((TT) & 7) * 4 + 3)) & 1u) ? -INFINITY : 0.25f * acc_[3]; \
    sh[TT][0] = pk2h(s0_, s1_); sh[TT][1] = pk2h(s2_, s3_); \
    mx = fmaxf(mx, fmaxf(fmaxf(s0_, s1_), fmaxf(s2_, s3_))); }

    wait_vm<8>();  // K0 ready
    QK_TILE(0, 0, 0); QK_TILE(0, 1, 1); QK_TILE(0, 2, 2); QK_TILE(0, 3, 3);
    ISSUE_K(0, 2);
    wait_vm<8>();  // K1 ready
    QK_TILE(1, 0, 4); QK_TILE(1, 1, 5); QK_TILE(1, 2, 6); QK_TILE(1, 3, 7);
    ISSUE_K(1, 3);
    wait_vm<8>();  // K2 ready
    QK_TILE(0, 0, 8); QK_TILE(0, 1, 9); QK_TILE(0, 2, 10); QK_TILE(0, 3, 11);
    wait_vm<0>();  // K3 ready
    QK_TILE(1, 0, 12); QK_TILE(1, 1, 13); QK_TILE(1, 2, 14); QK_TILE(1, 3, 15);

    // ---- softmax: row max across lg groups, then across waves ----
    mx = fmaxf(mx, __shfl_xor(mx, 16));
    mx = fmaxf(mx, __shfl_xor(mx, 32));
    if (lane < 16) red[0][w][lr] = mx;
    __syncthreads();
    const float gm = fmaxf(fmaxf(red[0][0][lr], red[0][1][lr]),
                           fmaxf(red[0][2][lr], red[0][3][lr]));

    // ---- exp + row sum; p stays packed fp16 (unnormalized) ----
    float lsum = 0.f;
#pragma unroll
    for (int tt = 0; tt < 16; ++tt) {
        half2v a = __builtin_bit_cast(half2v, sh[tt][0]);
        half2v b = __builtin_bit_cast(half2v, sh[tt][1]);
        float p0 = __expf((float)a[0] - gm);
        float p1 = __expf((float)a[1] - gm);
        float p2 = __expf((float)b[0] - gm);
        float p3 = __expf((float)b[1] - gm);
        lsum += (p0 + p1) + (p2 + p3);
        sh[tt][0] = pk2h(p0, p1);
        sh[tt][1] = pk2h(p2, p3);
    }
    lsum += __shfl_xor(lsum, 16);
    lsum += __shfl_xor(lsum, 32);
    if (lane < 16) red[1][w][lr] = lsum;
    __syncthreads();
    const float gsum = red[1][0][lr] + red[1][1][lr] + red[1][2][lr] + red[1][3][lr];
    const float rinv = 1.0f / gsum;

    // ---- PV: asm-pipelined V chunks (2 c-steps = 8 loads each) ----
    const unsigned short* vp = Vt + ((size_t)bh * 64 + lr) * L_ + w * 256 + lg * 8;
    f32x4 cacc[4] = {{0,0,0,0},{0,0,0,0},{0,0,0,0},{0,0,0,0}};
    unsigned short* pb = &u.pbuf[w][0];
    half8 vv[2][2][4];  // [buf][c-in-chunk][nt]
#define ISSUE_V(BUF, C) { \
    const unsigned short* b0_ = vp + (C) * 32; \
    const unsigned short* b1_ = b0_ + 16384; \
    const unsigned short* b2_ = b0_ + 32768; \
    const unsigned short* b3_ = b0_ + 49152; \
    gl_h8<0>(vv[BUF][0][0], b0_); gl_h8<64>(vv[BUF][1][0], b0_); \
    gl_h8<0>(vv[BUF][0][1], b1_); gl_h8<64>(vv[BUF][1][1], b1_); \
    gl_h8<0>(vv[BUF][0][2], b2_); gl_h8<64>(vv[BUF][1][2], b2_); \
    gl_h8<0>(vv[BUF][0][3], b3_); gl_h8<64>(vv[BUF][1][3], b3_); }
#define PV_C(BUF, H, C) { \
    uint2 pr0_; pr0_.x = sh[2 * (C)][0]; pr0_.y = sh[2 * (C)][1]; \
    *reinterpret_cast<uint2*>(&pb[lr * 40 + lg * 4]) = pr0_; \
    uint2 pr1_; pr1_.x = sh[2 * (C) + 1][0]; pr1_.y = sh[2 * (C) + 1][1]; \
    *reinterpret_cast<uint2*>(&pb[lr * 40 + 16 + lg * 4]) = pr1_; \
    half8 pa_ = *reinterpret_cast<const half8*>(&pb[lr * 40 + lg * 8]); \
    cacc[0] = __builtin_amdgcn_mfma_f32_16x16x32_f16(pa_, vv[BUF][H][0], cacc[0], 0, 0, 0); \
    cacc[1] = __builtin_amdgcn_mfma_f32_16x16x32_f16(pa_, vv[BUF][H][1], cacc[1], 0, 0, 0); \
    cacc[2] = __builtin_amdgcn_mfma_f32_16x16x32_f16(pa_, vv[BUF][H][2], cacc[2], 0, 0, 0); \
    cacc[3] = __builtin_amdgcn_mfma_f32_16x16x32_f16(pa_, vv[BUF][H][3], cacc[3], 0, 0, 0); }

    ISSUE_V(0, 0); ISSUE_V(1, 2);   // 16 outstanding
    wait_vm<8>();  PV_C(0, 0, 0); PV_C(0, 1, 1); ISSUE_V(0, 4);
    wait_vm<8>();  PV_C(1, 0, 2); PV_C(1, 1, 3); ISSUE_V(1, 6);
    wait_vm<8>();  PV_C(0, 0, 4); PV_C(0, 1, 5);
    wait_vm<0>();  PV_C(1, 0, 6); PV_C(1, 1, 7);

    // ---- attn write pass (normalized); all compiler vmem lives after the
    // last wait+sched_barrier so asm vmcnt accounting stays exact ----
#pragma unroll
    for (int tt = 0; tt < 16; ++tt) {
        half2v a = __builtin_bit_cast(half2v, sh[tt][0]);
        half2v b = __builtin_bit_cast(half2v, sh[tt][1]);
        float4 av;
        av.x = (float)a[0] * rinv; av.y = (float)a[1] * rinv;
        av.z = (float)b[0] * rinv; av.w = (float)b[1] * rinv;
        *reinterpret_cast<float4*>(&attn_out[rowbase + w * 256 + tt * 16 + lg * 4]) = av;
    }

    // ---- combine partial contexts across waves, normalize by 1/sum ----
    __syncthreads();  // all waves done with u.pbuf before u.ctxbuf overwrites
#pragma unroll
    for (int nt = 0; nt < 4; ++nt)
#pragma unroll
        for (int r = 0; r < 4; ++r)
            u.ctxbuf[w][lg * 4 + r][nt * 16 + lr] = cacc[nt][r];
    __syncthreads();
    {
        int e = tid * 4;
        int q = e >> 6, n = e & 63;
        float gs = red[1][0][q] + red[1][1][q] + red[1][2][q] + red[1][3][q];
        float rq = 1.0f / gs;
        float4 a0 = *reinterpret_cast<float4*>(&u.ctxbuf[0][q][n]);
        float4 a1 = *reinterpret_cast<float4*>(&u.ctxbuf[1][q][n]);
        float4 a2 = *reinterpret_cast<float4*>(&u.ctxbuf[2][q][n]);
        float4 a3 = *reinterpret_cast<float4*>(&u.ctxbuf[3][q][n]);
        float4 o;
        o.x = (a0.x + a1.x + a2.x + a3.x) * rq;
        o.y = (a0.y + a1.y + a2.y + a3.y) * rq;
        o.z = (a0.z + a1.z + a2.z + a3.z) * rq;
        o.w = (a0.w + a1.w + a2.w + a3.w) * rq;
        *reinterpret_cast<float4*>(&ctx_out[((size_t)bh * L_ + q0 + q) * DK_ + n]) = o;
    }
}

extern "C" void kernel_launch(void* const* d_in, const int* in_sizes, int n_in,
                              void* d_out, int out_size, void* d_ws, size_t ws_size,
                              hipStream_t stream) {
    const float* Q = (const float*)d_in[0];
    const float* K = (const float*)d_in[1];
    const float* V = (const float*)d_in[2];
    const int* mask = (const int*)d_in[3];
    float* ctx_out = (float*)d_out;
    float* attn_out = ctx_out + (size_t)BH_ * L_ * DK_;

    unsigned short* Kh = (unsigned short*)d_ws;
    unsigned short* Vt = Kh + (size_t)BH_ * L_ * DK_;

    hipLaunchKernelGGL(prep_k, dim3(4096), dim3(256), 0, stream, K, Kh);
    hipLaunchKernelGGL(prep_v, dim3(1024), dim3(256), 0, stream, V, Vt);
    hipLaunchKernelGGL(attn_main, dim3(64, 64), dim3(256), 0, stream,
                       Q, mask, Kh, Vt, ctx_out, attn_out);
}